// Round 20
// baseline (24.155 us; speedup 1.0000x reference)
//
#include <hip/hip_runtime.h>

#define Hd 256
#define NPSd 48
#define Sd 64
#define Nd (Sd*NPSd)
#define ROWS 4   // rows per block

// LDS-only barrier: no vmcnt drain, in-flight global loads survive it.
__device__ __forceinline__ void barrier_lds() {
  asm volatile("s_waitcnt lgkmcnt(0)" ::: "memory");
  __builtin_amdgcn_s_barrier();
}

// one DPP row_ror:N accumulate step; ENC is a compile-time constant
template<int ENC>
__device__ __forceinline__ float dpp_ror_add(float v) {
  int t = __builtin_amdgcn_update_dpp(0, __float_as_int(v), ENC, 0xF, 0xF, true);
  return v + __int_as_float(t);
}

// ---------------------------------------------------------------------------
// Fused kernel (R17 verbatim + block early-exit + B-chunk hoist):
// 768 blocks x 256 thr; block = 4 rows, 1 scene.
// Phase A: pt = W2*t+b2, v = W1^T*pt -> LDS, cr -> LDS.
// Phase B: wave w streams row w's mask-compacted j-list, 3-deep A/B/C
// register pipeline, transposed 4-row chunk reduce (xor32/xor16 + DPP ror).
__global__ __launch_bounds__(256) void fused_kernel(
    const float* __restrict__ spatial,
    const float* __restrict__ temporal,
    const float* __restrict__ W1_w, const float* __restrict__ W1_b,
    const float* __restrict__ W2_w, const float* __restrict__ W2_b,
    const int* __restrict__ ts_mask,
    float* __restrict__ out) {
  __shared__ float t_lds[ROWS][4][72];
  __shared__ float pt_lds[ROWS][64];
  __shared__ float crp[4][ROWS];
  __shared__ float vred[ROWS][4][Hd];   // 16 KB
  __shared__ float vvL[ROWS][Hd];       // 4 KB
  __shared__ float crL[ROWS];

  int row0 = blockIdx.x * ROWS;
  int s    = row0 / NPSd;
  int i0   = row0 - s*NPSd;
  int tid  = threadIdx.x;
  int wave = tid >> 6, lane = tid & 63;
  bool bit16 = (lane & 16) != 0;
  bool bit32 = (lane & 32) != 0;

  // ---- mask + early-exit (block-uniform, before any barrier)
  int ml = lane < NPSd ? lane : NPSd-1;
  int mv = ts_mask[s*NPSd + ml];
  unsigned long long mb = __ballot(mv == 1 && lane < NPSd);
  int nv = __popcll(mb);
  unsigned rbits = (unsigned)((mb >> (unsigned)i0) & 0xFull);
  int row  = row0 + wave;
  int irow = i0 + wave;
  if (rbits == 0u || nv <= 1) {
    float4 z = make_float4(0.f,0.f,0.f,0.f);
    *(float4*)(out + (size_t)row*Hd + (lane<<2)) = z;
    return;
  }
  float scale = (float)nv * 0.125f;   // ne / sqrt(A=64)
  bool rowv = (rbits >> (unsigned)wave) & 1u;

  // in-register compact j-list: lane l = l-th set bit of mb
  unsigned long long m = mb;
  int k = lane, jbit = 0, pc;
  pc = __popcll(m & 0xFFFFFFFFull); if (k >= pc) { jbit += 32; k -= pc; m >>= 32; }
  pc = __popcll(m & 0xFFFFull);     if (k >= pc) { jbit += 16; k -= pc; m >>= 16; }
  pc = __popcll(m & 0xFFull);       if (k >= pc) { jbit += 8;  k -= pc; m >>= 8; }
  pc = __popcll(m & 0xFull);        if (k >= pc) { jbit += 4;  k -= pc; m >>= 4; }
  pc = __popcll(m & 0x3ull);        if (k >= pc) { jbit += 2;  k -= pc; m >>= 2; }
  pc = (int)(m & 1ull);             if (k >= pc) { jbit += 1; }

  // ---------------- Phase A: prep (R17 structure) ----------------
  int al = (wave<<4) + (lane & 15);
  int q  = lane >> 4;
  float b1v = W1_b[al];
  float b2v = W2_b[al];

  {
    int r = tid >> 6, h4 = (tid & 63) << 2;
    float4 tv = *(const float4*)(temporal + (size_t)(row0 + r)*Hd + h4);
    *(float4*)&t_lds[r][h4 >> 6][h4 & 63] = tv;
  }

  float4 w2r[16];
#pragma unroll
  for (int mm = 0; mm < 16; ++mm)
    w2r[mm] = *(const float4*)(W2_w + (size_t)al*Hd + q*64 + mm*4);

  __syncthreads();

#pragma unroll
  for (int r = 0; r < ROWS; ++r) {
    float p = 0.f;
#pragma unroll
    for (int mm = 0; mm < 16; ++mm) {
      float4 wv = w2r[mm];
      p += wv.x * t_lds[r][q][mm*4+0];
      p += wv.y * t_lds[r][q][mm*4+1];
      p += wv.z * t_lds[r][q][mm*4+2];
      p += wv.w * t_lds[r][q][mm*4+3];
    }
    p += __shfl_xor(p, 16);
    p += __shfl_xor(p, 32);
    float pfull = p + b2v;
    float cb = pfull * b1v;
    cb += __shfl_xor(cb, 1);
    cb += __shfl_xor(cb, 2);
    cb += __shfl_xor(cb, 4);
    cb += __shfl_xor(cb, 8);
    if (lane < 16) pt_lds[r][(wave<<4) + lane] = pfull;
    if (lane == 0) crp[wave][r] = cb;
  }
  barrier_lds();

  float4 w1r[16];
#pragma unroll
  for (int j = 0; j < 16; ++j)
    w1r[j] = *(const float4*)(W1_w + (size_t)((wave<<4)+j)*Hd + (lane<<2));
  __builtin_amdgcn_sched_barrier(0);

  const float* rb = spatial + (size_t)row*NPSd*Hd;
  int nc = (nv + 3) >> 2;             // chunks of 4 slots
  float4 A[4], B[4], C[4];
  int jA[4], jB[4], jC[4];

#define ISSUE(DST, JD, Ch)                                                  \
  { _Pragma("unroll")                                                       \
    for (int rr = 0; rr < 4; ++rr) {                                        \
      int slot = (Ch)*4 + rr;                                               \
      int ss = slot < nv ? slot : 0;                                        \
      int j = __builtin_amdgcn_readlane(jbit, ss);                          \
      JD[rr] = slot < nv ? j : -1;                                          \
      DST[rr] = *(const float4*)(rb + (size_t)j*Hd + (lane << 2));          \
    }                                                                       \
    __builtin_amdgcn_sched_barrier(0); }

  if (rowv) {
    ISSUE(A, jA, 0);                  // chunks 0+1 in flight under v-MACs
    if (nc > 1) ISSUE(B, jB, 1);
  }

#pragma unroll
  for (int r = 0; r < ROWS; ++r) {
    float4 v4 = make_float4(0.f,0.f,0.f,0.f);
#pragma unroll
    for (int j = 0; j < 16; ++j) {
      float pj = pt_lds[r][(wave<<4)+j];
      float4 wv = w1r[j];
      v4.x += pj*wv.x; v4.y += pj*wv.y; v4.z += pj*wv.z; v4.w += pj*wv.w;
    }
    *(float4*)&vred[r][wave][lane<<2] = v4;
  }
  barrier_lds();

#pragma unroll
  for (int r = 0; r < ROWS; ++r)
    vvL[r][tid] = vred[r][0][tid] + vred[r][1][tid]
                + vred[r][2][tid] + vred[r][3][tid];
  if (tid < ROWS)
    crL[tid] = crp[0][tid] + crp[1][tid] + crp[2][tid] + crp[3][tid];
  barrier_lds();

  // ---------------- Phase B: stream (transposed chunk reduce) -------------
  float4 vv = *(const float4*)&vvL[wave][lane<<2];
  float cr = crL[wave];
  float k1 = scale * 1.44269504f;        // log2(e)*scale
  float k2 = cr * scale * 1.44269504f;
  float4 o4 = make_float4(0.f, 0.f, 0.f, 0.f);
  float den = 0.f;

#define DO_CHUNK(CUR, JC2)                                                  \
  { float q0 = CUR[0].x*vv.x + CUR[0].y*vv.y + CUR[0].z*vv.z + CUR[0].w*vv.w;\
    float q1 = CUR[1].x*vv.x + CUR[1].y*vv.y + CUR[1].z*vv.z + CUR[1].w*vv.w;\
    float q2 = CUR[2].x*vv.x + CUR[2].y*vv.y + CUR[2].z*vv.z + CUR[2].w*vv.w;\
    float q3 = CUR[3].x*vv.x + CUR[3].y*vv.y + CUR[3].z*vv.z + CUR[3].w*vv.w;\
    float s0 = (bit32 ? q2 : q0) + __shfl_xor((bit32 ? q0 : q2), 32);       \
    float s1 = (bit32 ? q3 : q1) + __shfl_xor((bit32 ? q1 : q3), 32);       \
    float tt = (bit16 ? s1 : s0) + __shfl_xor((bit16 ? s0 : s1), 16);       \
    tt = dpp_ror_add<0x121>(tt);                                            \
    tt = dpp_ror_add<0x122>(tt);                                            \
    tt = dpp_ror_add<0x124>(tt);                                            \
    tt = dpp_ror_add<0x128>(tt);                                            \
    int jg = bit32 ? (bit16 ? JC2[3] : JC2[2]) : (bit16 ? JC2[1] : JC2[0]); \
    bool vg = (jg >= 0) && (jg != irow);                                    \
    float nj = vg ? __builtin_exp2f(tt * k1 + k2) : 0.f;                    \
    float nB = __shfl_xor(nj, 16);                                          \
    float nC = __shfl_xor(nj, 32);                                          \
    float nD = __shfl_xor(nB, 32);                                          \
    den += (nj + nB) + (nC + nD);                                           \
    float n0 = bit32 ? (bit16 ? nD : nC) : (bit16 ? nB : nj);               \
    float n1 = bit32 ? (bit16 ? nC : nD) : (bit16 ? nj : nB);               \
    float n2 = bit32 ? (bit16 ? nB : nj) : (bit16 ? nD : nC);               \
    float n3 = bit32 ? (bit16 ? nj : nB) : (bit16 ? nC : nD);               \
    o4.x += n0*CUR[0].x; o4.y += n0*CUR[0].y; o4.z += n0*CUR[0].z; o4.w += n0*CUR[0].w; \
    o4.x += n1*CUR[1].x; o4.y += n1*CUR[1].y; o4.z += n1*CUR[1].z; o4.w += n1*CUR[1].w; \
    o4.x += n2*CUR[2].x; o4.y += n2*CUR[2].y; o4.z += n2*CUR[2].z; o4.w += n2*CUR[2].w; \
    o4.x += n3*CUR[3].x; o4.y += n3*CUR[3].y; o4.z += n3*CUR[3].z; o4.w += n3*CUR[3].w; }

  if (rowv) {
    if (nc > 2) ISSUE(C, jC, 2);
    int cc = 0;
    while (true) {
      DO_CHUNK(A, jA); if (cc + 3 < nc) ISSUE(A, jA, cc + 3);
      ++cc; if (cc >= nc) break;
      DO_CHUNK(B, jB); if (cc + 3 < nc) ISSUE(B, jB, cc + 3);
      ++cc; if (cc >= nc) break;
      DO_CHUNK(C, jC); if (cc + 3 < nc) ISSUE(C, jC, cc + 3);
      ++cc; if (cc >= nc) break;
    }
  }
#undef ISSUE
#undef DO_CHUNK

  float inv = den > 0.f ? 1.f/den : 0.f;
  o4.x *= inv; o4.y *= inv; o4.z *= inv; o4.w *= inv;
  *(float4*)(out + (size_t)row*Hd + (lane<<2)) = o4;
}

// ---------------------------------------------------------------------------
extern "C" void kernel_launch(void* const* d_in, const int* in_sizes, int n_in,
                              void* d_out, int out_size, void* d_ws, size_t ws_size,
                              hipStream_t stream) {
  const float* spatial  = (const float*)d_in[0];
  const float* temporal = (const float*)d_in[1];
  const float* W1_w     = (const float*)d_in[2];
  const float* W1_b     = (const float*)d_in[3];
  const float* W2_w     = (const float*)d_in[4];
  const float* W2_b     = (const float*)d_in[5];
  const int*   ts_mask  = (const int*)d_in[6];
  float* out = (float*)d_out;

  fused_kernel<<<Nd/ROWS, 256, 0, stream>>>(spatial, temporal, W1_w, W1_b,
                                            W2_w, W2_b, ts_mask, out);
}

// Round 21
// 21.130 us; speedup vs baseline: 1.1432x; 1.1432x over previous
//
#include <hip/hip_runtime.h>

#define Hd 256
#define NPSd 48
#define Sd 64
#define Nd (Sd*NPSd)
#define ROWS 4   // rows per block

// LDS-only barrier: no vmcnt drain, in-flight global loads survive it.
__device__ __forceinline__ void barrier_lds() {
  asm volatile("s_waitcnt lgkmcnt(0)" ::: "memory");
  __builtin_amdgcn_s_barrier();
}

// one DPP row_ror:N accumulate step; ENC must be a compile-time constant
template<int ENC>
__device__ __forceinline__ float dpp_ror_add(float v) {
  int t = __builtin_amdgcn_update_dpp(0, __float_as_int(v), ENC, 0xF, 0xF, true);
  return v + __int_as_float(t);
}

// ---------------------------------------------------------------------------
// Fused kernel (R17 verbatim — best measured: 21.27 us):
// 768 blocks x 256 thr; block = 4 rows, 1 scene.
// Phase A: pt = W2*t+b2, v = W1^T*pt -> LDS, cr -> LDS.
// Phase B: wave w streams row w's mask-compacted j-list, 3-deep A/B/C
// register pipeline. Transposed 4-row chunk reduce: 2x sel+xor32,
// 1x sel+xor16, 4x DPP row_ror {1,2,4,8}; one exp per lane; 3 shfl
// broadcast nj back; static cndmask tree routes to aggregation fmas.
__global__ __launch_bounds__(256) void fused_kernel(
    const float* __restrict__ spatial,
    const float* __restrict__ temporal,
    const float* __restrict__ W1_w, const float* __restrict__ W1_b,
    const float* __restrict__ W2_w, const float* __restrict__ W2_b,
    const int* __restrict__ ts_mask,
    float* __restrict__ out) {
  __shared__ float t_lds[ROWS][4][72];
  __shared__ float pt_lds[ROWS][64];
  __shared__ float crp[4][ROWS];
  __shared__ float vred[ROWS][4][Hd];   // 16 KB
  __shared__ float vvL[ROWS][Hd];       // 4 KB
  __shared__ float crL[ROWS];

  int row0 = blockIdx.x * ROWS;
  int s    = row0 / NPSd;
  int i0   = row0 - s*NPSd;
  int tid  = threadIdx.x;
  int wave = tid >> 6, lane = tid & 63;
  bool bit16 = (lane & 16) != 0;
  bool bit32 = (lane & 32) != 0;

  // ---- mask + in-register compact j-list (cheap, before prep)
  int ml = lane < NPSd ? lane : NPSd-1;
  int mv = ts_mask[s*NPSd + ml];
  unsigned long long mb = __ballot(mv == 1 && lane < NPSd);
  int nv = __popcll(mb);
  float scale = (float)nv * 0.125f;   // ne / sqrt(A=64)
  int row  = row0 + wave;
  int irow = i0 + wave;
  bool rowv = ((mb >> (unsigned)irow) & 1ULL) && nv > 1;

  unsigned long long m = mb;
  int k = lane, jbit = 0, pc;
  pc = __popcll(m & 0xFFFFFFFFull); if (k >= pc) { jbit += 32; k -= pc; m >>= 32; }
  pc = __popcll(m & 0xFFFFull);     if (k >= pc) { jbit += 16; k -= pc; m >>= 16; }
  pc = __popcll(m & 0xFFull);       if (k >= pc) { jbit += 8;  k -= pc; m >>= 8; }
  pc = __popcll(m & 0xFull);        if (k >= pc) { jbit += 4;  k -= pc; m >>= 4; }
  pc = __popcll(m & 0x3ull);        if (k >= pc) { jbit += 2;  k -= pc; m >>= 2; }
  pc = (int)(m & 1ull);             if (k >= pc) { jbit += 1; }

  // ---------------- Phase A: prep (proven structure) ----------------
  int al = (wave<<4) + (lane & 15);
  int q  = lane >> 4;
  float b1v = W1_b[al];
  float b2v = W2_b[al];

  {
    int r = tid >> 6, h4 = (tid & 63) << 2;
    float4 tv = *(const float4*)(temporal + (size_t)(row0 + r)*Hd + h4);
    *(float4*)&t_lds[r][h4 >> 6][h4 & 63] = tv;
  }

  float4 w2r[16];
#pragma unroll
  for (int mm = 0; mm < 16; ++mm)
    w2r[mm] = *(const float4*)(W2_w + (size_t)al*Hd + q*64 + mm*4);

  __syncthreads();

#pragma unroll
  for (int r = 0; r < ROWS; ++r) {
    float p = 0.f;
#pragma unroll
    for (int mm = 0; mm < 16; ++mm) {
      float4 wv = w2r[mm];
      p += wv.x * t_lds[r][q][mm*4+0];
      p += wv.y * t_lds[r][q][mm*4+1];
      p += wv.z * t_lds[r][q][mm*4+2];
      p += wv.w * t_lds[r][q][mm*4+3];
    }
    p += __shfl_xor(p, 16);
    p += __shfl_xor(p, 32);
    float pfull = p + b2v;
    float cb = pfull * b1v;
    cb += __shfl_xor(cb, 1);
    cb += __shfl_xor(cb, 2);
    cb += __shfl_xor(cb, 4);
    cb += __shfl_xor(cb, 8);
    if (lane < 16) pt_lds[r][(wave<<4) + lane] = pfull;
    if (lane == 0) crp[wave][r] = cb;
  }
  barrier_lds();

  float4 w1r[16];
#pragma unroll
  for (int j = 0; j < 16; ++j)
    w1r[j] = *(const float4*)(W1_w + (size_t)((wave<<4)+j)*Hd + (lane<<2));
  __builtin_amdgcn_sched_barrier(0);

  const float* rb = spatial + (size_t)row*NPSd*Hd;
  int nc = (nv + 3) >> 2;             // chunks of 4 slots
  float4 A[4], B[4], C[4];
  int jA[4], jB[4], jC[4];

#define ISSUE(DST, JD, Ch)                                                  \
  { _Pragma("unroll")                                                       \
    for (int rr = 0; rr < 4; ++rr) {                                        \
      int slot = (Ch)*4 + rr;                                               \
      int ss = slot < nv ? slot : 0;                                        \
      int j = __builtin_amdgcn_readlane(jbit, ss);                          \
      JD[rr] = slot < nv ? j : -1;                                          \
      DST[rr] = *(const float4*)(rb + (size_t)j*Hd + (lane << 2));          \
    }                                                                       \
    __builtin_amdgcn_sched_barrier(0); }

  if (rowv) { ISSUE(A, jA, 0); }      // first chunk in flight under v-MACs

#pragma unroll
  for (int r = 0; r < ROWS; ++r) {
    float4 v4 = make_float4(0.f,0.f,0.f,0.f);
#pragma unroll
    for (int j = 0; j < 16; ++j) {
      float pj = pt_lds[r][(wave<<4)+j];
      float4 wv = w1r[j];
      v4.x += pj*wv.x; v4.y += pj*wv.y; v4.z += pj*wv.z; v4.w += pj*wv.w;
    }
    *(float4*)&vred[r][wave][lane<<2] = v4;
  }
  barrier_lds();

#pragma unroll
  for (int r = 0; r < ROWS; ++r)
    vvL[r][tid] = vred[r][0][tid] + vred[r][1][tid]
                + vred[r][2][tid] + vred[r][3][tid];
  if (tid < ROWS)
    crL[tid] = crp[0][tid] + crp[1][tid] + crp[2][tid] + crp[3][tid];
  barrier_lds();

  // ---------------- Phase B: stream (transposed chunk reduce) -------------
  float4 vv = *(const float4*)&vvL[wave][lane<<2];
  float cr = crL[wave];
  float k1 = scale * 1.44269504f;        // log2(e)*scale
  float k2 = cr * scale * 1.44269504f;
  float4 o4 = make_float4(0.f, 0.f, 0.f, 0.f);
  float den = 0.f;

#define DO_CHUNK(CUR, JC2)                                                  \
  { float q0 = CUR[0].x*vv.x + CUR[0].y*vv.y + CUR[0].z*vv.z + CUR[0].w*vv.w;\
    float q1 = CUR[1].x*vv.x + CUR[1].y*vv.y + CUR[1].z*vv.z + CUR[1].w*vv.w;\
    float q2 = CUR[2].x*vv.x + CUR[2].y*vv.y + CUR[2].z*vv.z + CUR[2].w*vv.w;\
    float q3 = CUR[3].x*vv.x + CUR[3].y*vv.y + CUR[3].z*vv.z + CUR[3].w*vv.w;\
    float s0 = (bit32 ? q2 : q0) + __shfl_xor((bit32 ? q0 : q2), 32);       \
    float s1 = (bit32 ? q3 : q1) + __shfl_xor((bit32 ? q1 : q3), 32);       \
    float tt = (bit16 ? s1 : s0) + __shfl_xor((bit16 ? s0 : s1), 16);       \
    tt = dpp_ror_add<0x121>(tt);                                            \
    tt = dpp_ror_add<0x122>(tt);                                            \
    tt = dpp_ror_add<0x124>(tt);                                            \
    tt = dpp_ror_add<0x128>(tt);                                            \
    int jg = bit32 ? (bit16 ? JC2[3] : JC2[2]) : (bit16 ? JC2[1] : JC2[0]); \
    bool vg = (jg >= 0) && (jg != irow);                                    \
    float nj = vg ? __builtin_exp2f(tt * k1 + k2) : 0.f;                    \
    float nB = __shfl_xor(nj, 16);                                          \
    float nC = __shfl_xor(nj, 32);                                          \
    float nD = __shfl_xor(nB, 32);                                          \
    den += (nj + nB) + (nC + nD);                                           \
    float n0 = bit32 ? (bit16 ? nD : nC) : (bit16 ? nB : nj);               \
    float n1 = bit32 ? (bit16 ? nC : nD) : (bit16 ? nj : nB);               \
    float n2 = bit32 ? (bit16 ? nB : nj) : (bit16 ? nD : nC);               \
    float n3 = bit32 ? (bit16 ? nj : nB) : (bit16 ? nC : nD);               \
    o4.x += n0*CUR[0].x; o4.y += n0*CUR[0].y; o4.z += n0*CUR[0].z; o4.w += n0*CUR[0].w; \
    o4.x += n1*CUR[1].x; o4.y += n1*CUR[1].y; o4.z += n1*CUR[1].z; o4.w += n1*CUR[1].w; \
    o4.x += n2*CUR[2].x; o4.y += n2*CUR[2].y; o4.z += n2*CUR[2].z; o4.w += n2*CUR[2].w; \
    o4.x += n3*CUR[3].x; o4.y += n3*CUR[3].y; o4.z += n3*CUR[3].z; o4.w += n3*CUR[3].w; }

  if (rowv) {
    if (nc > 1) ISSUE(B, jB, 1);
    if (nc > 2) ISSUE(C, jC, 2);
    int cc = 0;
    while (true) {
      DO_CHUNK(A, jA); if (cc + 3 < nc) ISSUE(A, jA, cc + 3);
      ++cc; if (cc >= nc) break;
      DO_CHUNK(B, jB); if (cc + 3 < nc) ISSUE(B, jB, cc + 3);
      ++cc; if (cc >= nc) break;
      DO_CHUNK(C, jC); if (cc + 3 < nc) ISSUE(C, jC, cc + 3);
      ++cc; if (cc >= nc) break;
    }
  }
#undef ISSUE
#undef DO_CHUNK

  float inv = den > 0.f ? 1.f/den : 0.f;
  o4.x *= inv; o4.y *= inv; o4.z *= inv; o4.w *= inv;
  *(float4*)(out + (size_t)row*Hd + (lane<<2)) = o4;
}

// ---------------------------------------------------------------------------
extern "C" void kernel_launch(void* const* d_in, const int* in_sizes, int n_in,
                              void* d_out, int out_size, void* d_ws, size_t ws_size,
                              hipStream_t stream) {
  const float* spatial  = (const float*)d_in[0];
  const float* temporal = (const float*)d_in[1];
  const float* W1_w     = (const float*)d_in[2];
  const float* W1_b     = (const float*)d_in[3];
  const float* W2_w     = (const float*)d_in[4];
  const float* W2_b     = (const float*)d_in[5];
  const int*   ts_mask  = (const int*)d_in[6];
  float* out = (float*)d_out;

  fused_kernel<<<Nd/ROWS, 256, 0, stream>>>(spatial, temporal, W1_w, W1_b,
                                            W2_w, W2_b, ts_mask, out);
}

// Round 22
// 21.128 us; speedup vs baseline: 1.1433x; 1.0001x over previous
//
#include <hip/hip_runtime.h>

#define Hd 256
#define NPSd 48
#define Sd 64
#define Nd (Sd*NPSd)
#define ROWS 4   // rows per block

// LDS-only barrier: no vmcnt drain, in-flight global loads survive it.
__device__ __forceinline__ void barrier_lds() {
  asm volatile("s_waitcnt lgkmcnt(0)" ::: "memory");
  __builtin_amdgcn_s_barrier();
}

// one DPP row_ror:N accumulate step; ENC must be a compile-time constant
template<int ENC>
__device__ __forceinline__ float dpp_ror_add(float v) {
  int t = __builtin_amdgcn_update_dpp(0, __float_as_int(v), ENC, 0xF, 0xF, true);
  return v + __int_as_float(t);
}

// ---------------------------------------------------------------------------
// Fused kernel (R17 + ONE lever: chunk-A prefetch moved into the prologue):
// 768 blocks x 256 thr; block = 4 rows, 1 scene.
// Phase A: pt = W2*t+b2, v = W1^T*pt -> LDS, cr -> LDS.
//   Chunk A of this wave's row is issued right after the w2r loads, so its
//   HBM latency hides under phase-1 MACs; the first barrier is lgkm-only so
//   the prefetch survives it (syncthreads would vmcnt(0)-drain it).
// Phase B: wave w streams row w's mask-compacted j-list, 3-deep A/B/C
// register pipeline, transposed 4-row chunk reduce (xor32/xor16 + DPP ror).
__global__ __launch_bounds__(256) void fused_kernel(
    const float* __restrict__ spatial,
    const float* __restrict__ temporal,
    const float* __restrict__ W1_w, const float* __restrict__ W1_b,
    const float* __restrict__ W2_w, const float* __restrict__ W2_b,
    const int* __restrict__ ts_mask,
    float* __restrict__ out) {
  __shared__ float t_lds[ROWS][4][72];
  __shared__ float pt_lds[ROWS][64];
  __shared__ float crp[4][ROWS];
  __shared__ float vred[ROWS][4][Hd];   // 16 KB
  __shared__ float vvL[ROWS][Hd];       // 4 KB
  __shared__ float crL[ROWS];

  int row0 = blockIdx.x * ROWS;
  int s    = row0 / NPSd;
  int i0   = row0 - s*NPSd;
  int tid  = threadIdx.x;
  int wave = tid >> 6, lane = tid & 63;
  bool bit16 = (lane & 16) != 0;
  bool bit32 = (lane & 32) != 0;

  // ---- mask + in-register compact j-list (cheap, before prep)
  int ml = lane < NPSd ? lane : NPSd-1;
  int mv = ts_mask[s*NPSd + ml];
  unsigned long long mb = __ballot(mv == 1 && lane < NPSd);
  int nv = __popcll(mb);
  float scale = (float)nv * 0.125f;   // ne / sqrt(A=64)
  int row  = row0 + wave;
  int irow = i0 + wave;
  bool rowv = ((mb >> (unsigned)irow) & 1ULL) && nv > 1;

  unsigned long long m = mb;
  int k = lane, jbit = 0, pc;
  pc = __popcll(m & 0xFFFFFFFFull); if (k >= pc) { jbit += 32; k -= pc; m >>= 32; }
  pc = __popcll(m & 0xFFFFull);     if (k >= pc) { jbit += 16; k -= pc; m >>= 16; }
  pc = __popcll(m & 0xFFull);       if (k >= pc) { jbit += 8;  k -= pc; m >>= 8; }
  pc = __popcll(m & 0xFull);        if (k >= pc) { jbit += 4;  k -= pc; m >>= 4; }
  pc = __popcll(m & 0x3ull);        if (k >= pc) { jbit += 2;  k -= pc; m >>= 2; }
  pc = (int)(m & 1ull);             if (k >= pc) { jbit += 1; }

  const float* rb = spatial + (size_t)row*NPSd*Hd;
  int nc = (nv + 3) >> 2;             // chunks of 4 slots
  float4 A[4], B[4], C[4];
  int jA[4], jB[4], jC[4];

#define ISSUE(DST, JD, Ch)                                                  \
  { _Pragma("unroll")                                                       \
    for (int rr = 0; rr < 4; ++rr) {                                        \
      int slot = (Ch)*4 + rr;                                               \
      int ss = slot < nv ? slot : 0;                                        \
      int j = __builtin_amdgcn_readlane(jbit, ss);                          \
      JD[rr] = slot < nv ? j : -1;                                          \
      DST[rr] = *(const float4*)(rb + (size_t)j*Hd + (lane << 2));          \
    }                                                                       \
    __builtin_amdgcn_sched_barrier(0); }

  // ---------------- Phase A: prep (R17 structure) ----------------
  int al = (wave<<4) + (lane & 15);
  int q  = lane >> 4;
  float b1v = W1_b[al];
  float b2v = W2_b[al];

  {
    int r = tid >> 6, h4 = (tid & 63) << 2;
    float4 tv = *(const float4*)(temporal + (size_t)(row0 + r)*Hd + h4);
    *(float4*)&t_lds[r][h4 >> 6][h4 & 63] = tv;
  }

  float4 w2r[16];
#pragma unroll
  for (int mm = 0; mm < 16; ++mm)
    w2r[mm] = *(const float4*)(W2_w + (size_t)al*Hd + q*64 + mm*4);
  __builtin_amdgcn_sched_barrier(0);

  // ---- THE LEVER: chunk-A prefetch issued here, hides under phase-1
  if (rowv) { ISSUE(A, jA, 0); }

  barrier_lds();                      // t_lds ready; prefetch survives

#pragma unroll
  for (int r = 0; r < ROWS; ++r) {
    float p = 0.f;
#pragma unroll
    for (int mm = 0; mm < 16; ++mm) {
      float4 wv = w2r[mm];
      p += wv.x * t_lds[r][q][mm*4+0];
      p += wv.y * t_lds[r][q][mm*4+1];
      p += wv.z * t_lds[r][q][mm*4+2];
      p += wv.w * t_lds[r][q][mm*4+3];
    }
    p += __shfl_xor(p, 16);
    p += __shfl_xor(p, 32);
    float pfull = p + b2v;
    float cb = pfull * b1v;
    cb += __shfl_xor(cb, 1);
    cb += __shfl_xor(cb, 2);
    cb += __shfl_xor(cb, 4);
    cb += __shfl_xor(cb, 8);
    if (lane < 16) pt_lds[r][(wave<<4) + lane] = pfull;
    if (lane == 0) crp[wave][r] = cb;
  }
  barrier_lds();

  float4 w1r[16];
#pragma unroll
  for (int j = 0; j < 16; ++j)
    w1r[j] = *(const float4*)(W1_w + (size_t)((wave<<4)+j)*Hd + (lane<<2));
  __builtin_amdgcn_sched_barrier(0);

#pragma unroll
  for (int r = 0; r < ROWS; ++r) {
    float4 v4 = make_float4(0.f,0.f,0.f,0.f);
#pragma unroll
    for (int j = 0; j < 16; ++j) {
      float pj = pt_lds[r][(wave<<4)+j];
      float4 wv = w1r[j];
      v4.x += pj*wv.x; v4.y += pj*wv.y; v4.z += pj*wv.z; v4.w += pj*wv.w;
    }
    *(float4*)&vred[r][wave][lane<<2] = v4;
  }
  barrier_lds();

#pragma unroll
  for (int r = 0; r < ROWS; ++r)
    vvL[r][tid] = vred[r][0][tid] + vred[r][1][tid]
                + vred[r][2][tid] + vred[r][3][tid];
  if (tid < ROWS)
    crL[tid] = crp[0][tid] + crp[1][tid] + crp[2][tid] + crp[3][tid];
  barrier_lds();

  // ---------------- Phase B: stream (transposed chunk reduce) -------------
  float4 vv = *(const float4*)&vvL[wave][lane<<2];
  float cr = crL[wave];
  float k1 = scale * 1.44269504f;        // log2(e)*scale
  float k2 = cr * scale * 1.44269504f;
  float4 o4 = make_float4(0.f, 0.f, 0.f, 0.f);
  float den = 0.f;

#define DO_CHUNK(CUR, JC2)                                                  \
  { float q0 = CUR[0].x*vv.x + CUR[0].y*vv.y + CUR[0].z*vv.z + CUR[0].w*vv.w;\
    float q1 = CUR[1].x*vv.x + CUR[1].y*vv.y + CUR[1].z*vv.z + CUR[1].w*vv.w;\
    float q2 = CUR[2].x*vv.x + CUR[2].y*vv.y + CUR[2].z*vv.z + CUR[2].w*vv.w;\
    float q3 = CUR[3].x*vv.x + CUR[3].y*vv.y + CUR[3].z*vv.z + CUR[3].w*vv.w;\
    float s0 = (bit32 ? q2 : q0) + __shfl_xor((bit32 ? q0 : q2), 32);       \
    float s1 = (bit32 ? q3 : q1) + __shfl_xor((bit32 ? q1 : q3), 32);       \
    float tt = (bit16 ? s1 : s0) + __shfl_xor((bit16 ? s0 : s1), 16);       \
    tt = dpp_ror_add<0x121>(tt);                                            \
    tt = dpp_ror_add<0x122>(tt);                                            \
    tt = dpp_ror_add<0x124>(tt);                                            \
    tt = dpp_ror_add<0x128>(tt);                                            \
    int jg = bit32 ? (bit16 ? JC2[3] : JC2[2]) : (bit16 ? JC2[1] : JC2[0]); \
    bool vg = (jg >= 0) && (jg != irow);                                    \
    float nj = vg ? __builtin_exp2f(tt * k1 + k2) : 0.f;                    \
    float nB = __shfl_xor(nj, 16);                                          \
    float nC = __shfl_xor(nj, 32);                                          \
    float nD = __shfl_xor(nB, 32);                                          \
    den += (nj + nB) + (nC + nD);                                           \
    float n0 = bit32 ? (bit16 ? nD : nC) : (bit16 ? nB : nj);               \
    float n1 = bit32 ? (bit16 ? nC : nD) : (bit16 ? nj : nB);               \
    float n2 = bit32 ? (bit16 ? nB : nj) : (bit16 ? nD : nC);               \
    float n3 = bit32 ? (bit16 ? nj : nB) : (bit16 ? nC : nD);               \
    o4.x += n0*CUR[0].x; o4.y += n0*CUR[0].y; o4.z += n0*CUR[0].z; o4.w += n0*CUR[0].w; \
    o4.x += n1*CUR[1].x; o4.y += n1*CUR[1].y; o4.z += n1*CUR[1].z; o4.w += n1*CUR[1].w; \
    o4.x += n2*CUR[2].x; o4.y += n2*CUR[2].y; o4.z += n2*CUR[2].z; o4.w += n2*CUR[2].w; \
    o4.x += n3*CUR[3].x; o4.y += n3*CUR[3].y; o4.z += n3*CUR[3].z; o4.w += n3*CUR[3].w; }

  if (rowv) {
    if (nc > 1) ISSUE(B, jB, 1);
    if (nc > 2) ISSUE(C, jC, 2);
    int cc = 0;
    while (true) {
      DO_CHUNK(A, jA); if (cc + 3 < nc) ISSUE(A, jA, cc + 3);
      ++cc; if (cc >= nc) break;
      DO_CHUNK(B, jB); if (cc + 3 < nc) ISSUE(B, jB, cc + 3);
      ++cc; if (cc >= nc) break;
      DO_CHUNK(C, jC); if (cc + 3 < nc) ISSUE(C, jC, cc + 3);
      ++cc; if (cc >= nc) break;
    }
  }
#undef ISSUE
#undef DO_CHUNK

  float inv = den > 0.f ? 1.f/den : 0.f;
  o4.x *= inv; o4.y *= inv; o4.z *= inv; o4.w *= inv;
  *(float4*)(out + (size_t)row*Hd + (lane<<2)) = o4;
}

// ---------------------------------------------------------------------------
extern "C" void kernel_launch(void* const* d_in, const int* in_sizes, int n_in,
                              void* d_out, int out_size, void* d_ws, size_t ws_size,
                              hipStream_t stream) {
  const float* spatial  = (const float*)d_in[0];
  const float* temporal = (const float*)d_in[1];
  const float* W1_w     = (const float*)d_in[2];
  const float* W1_b     = (const float*)d_in[3];
  const float* W2_w     = (const float*)d_in[4];
  const float* W2_b     = (const float*)d_in[5];
  const int*   ts_mask  = (const int*)d_in[6];
  float* out = (float*)d_out;

  fused_kernel<<<Nd/ROWS, 256, 0, stream>>>(spatial, temporal, W1_w, W1_b,
                                            W2_w, W2_b, ts_mask, out);
}